// Round 8
// baseline (170.643 us; speedup 1.0000x reference)
//
#include <hip/hip_runtime.h>

// out[t][i][j] = sum_k x[i][k]*W[j][k] + bias[j] + sum_r low[t][i][r]*Bm[ti][j][r]
// low[t][i][r] = sum_k x[i][k]*A[ti][r][k]
// Base GEMM in single-stream fp16 MFMA (error ~1e-4, 100x under ref slack).
// v5: (a) xf production fused into lora_low (x read once), cvt handles W only;
//     (b) swapped-operand MFMA (accT = W·x^T = out^T fragment-wise) so each
//         lane holds 4 consecutive out columns -> float4 stores (4x fewer
//         store instructions).

typedef __attribute__((ext_vector_type(8))) _Float16 f16x8;
typedef __attribute__((ext_vector_type(4))) float f32x4;
typedef __attribute__((ext_vector_type(4))) unsigned short us4;
typedef __attribute__((ext_vector_type(8))) unsigned short us8;

namespace {
constexpr int kM = 16384, kDin = 1024, kDout = 1024, kR = 16, kT = 4;
// d_ws byte offsets
constexpr size_t OFF_XF  = 0;               // [16384][1024] fp16 = 32 MiB
constexpr size_t OFF_WF  = 33554432;        // [1024][1024] fp16 = 2 MiB
constexpr size_t OFF_LOW = 35651584;        // [4][16384][16] fp16 = 2 MiB
}

__device__ inline unsigned short f2h(float f) {
  _Float16 h = (_Float16)f;  // RNE
  return __builtin_bit_cast(unsigned short, h);
}
__device__ inline void gload_lds16(const void* g, void* l) {
  __builtin_amdgcn_global_load_lds(
      (const __attribute__((address_space(1))) unsigned int*)g,
      (__attribute__((address_space(3))) unsigned int*)l, 16, 0, 0);
}
__device__ inline f32x4 mfma_f16(f16x8 a, f16x8 b, f32x4 c) {
  return __builtin_amdgcn_mfma_f32_16x16x32_f16(a, b, c, 0, 0, 0);
}

// ---------------------------------------------------------------------------
// Kernel 1: fp32 -> fp16 for W only (x handled inside lora_low).
// ---------------------------------------------------------------------------
__global__ __launch_bounds__(256) void cvt_W(const float* __restrict__ W,
                                             unsigned short* __restrict__ wf) {
  constexpr int NW4 = kDout * kDin / 4;   // 262144
  const int stride = gridDim.x * blockDim.x;
  for (int j = blockIdx.x * blockDim.x + threadIdx.x; j < NW4; j += stride) {
    const float4 v = ((const float4*)W)[j];
    us4 h;
    h[0] = f2h(v.x); h[1] = f2h(v.y); h[2] = f2h(v.z); h[3] = f2h(v.w);
    ((us4*)wf)[j] = h;
  }
}

// ---------------------------------------------------------------------------
// Kernel 2: low[t][i][r] = x[i][:] . A[tuner[t]][r][:]  -> fp16
//           AND xf = fp16(x)   (x read from HBM exactly once)
// ---------------------------------------------------------------------------
__global__ __launch_bounds__(256) void lora_low(const float* __restrict__ x,
                                                const float* __restrict__ A,
                                                const int* __restrict__ tuner,
                                                unsigned short* __restrict__ lowb,
                                                unsigned short* __restrict__ xf) {
  __shared__ float xs[64][34];  // [k][row]
  __shared__ float as[64][66];  // [k][t*16+r]
  const int tid = threadIdx.x;
  const int i0  = blockIdx.x * 32;
  const int tx  = tid & 15;   // col group (4 cols)
  const int ty  = tid >> 4;   // row group (2 rows)
  float acc[2][4] = {{0.f, 0.f, 0.f, 0.f}, {0.f, 0.f, 0.f, 0.f}};

  for (int kt = 0; kt < kDin; kt += 64) {
    __syncthreads();
#pragma unroll
    for (int p = 0; p < 2; ++p) {  // x tile: 32 rows x 64 k
      const int f = tid + p * 256;
      const int row = f >> 4, kq = (f & 15) * 4;
      const float4 v = *(const float4*)(x + (size_t)(i0 + row) * kDin + kt + kq);
      xs[kq + 0][row] = v.x; xs[kq + 1][row] = v.y;
      xs[kq + 2][row] = v.z; xs[kq + 3][row] = v.w;
      us4 h;                       // fused fp16 conversion of x
      h[0] = f2h(v.x); h[1] = f2h(v.y); h[2] = f2h(v.z); h[3] = f2h(v.w);
      *(us4*)(xf + (size_t)(i0 + row) * kDin + kt + kq) = h;
    }
#pragma unroll
    for (int p = 0; p < 4; ++p) {  // A tile: 64 (t,r) rows x 64 k
      const int f = tid + p * 256;
      const int ar = f >> 4, kq = (f & 15) * 4;
      const int ti = tuner[ar >> 4];
      const float4 v = *(const float4*)(A + ((size_t)ti * kR + (ar & 15)) * kDin + kt + kq);
      as[kq + 0][ar] = v.x; as[kq + 1][ar] = v.y;
      as[kq + 2][ar] = v.z; as[kq + 3][ar] = v.w;
    }
    __syncthreads();
#pragma unroll 8
    for (int k = 0; k < 64; ++k) {
      const float a0 = xs[k][ty * 2], a1 = xs[k][ty * 2 + 1];
      const float b0 = as[k][tx * 4], b1 = as[k][tx * 4 + 1];
      const float b2 = as[k][tx * 4 + 2], b3 = as[k][tx * 4 + 3];
      acc[0][0] += a0 * b0; acc[0][1] += a0 * b1; acc[0][2] += a0 * b2; acc[0][3] += a0 * b3;
      acc[1][0] += a1 * b0; acc[1][1] += a1 * b1; acc[1][2] += a1 * b2; acc[1][3] += a1 * b3;
    }
  }
  // col c = tx*4+j  ->  t = tx>>2, r = (tx&3)*4+j
#pragma unroll
  for (int ii = 0; ii < 2; ++ii) {
    us4 o;
#pragma unroll
    for (int j = 0; j < 4; ++j) o[j] = f2h(acc[ii][j]);
    *(us4*)(lowb + ((size_t)(tx >> 2) * kM + i0 + ty * 2 + ii) * kR + (tx & 3) * 4) = o;
  }
}

// ---------------------------------------------------------------------------
// Kernel 3: main fp16 MFMA GEMM (128x128, BK=32) + per-t rank-16 epilogue.
// Swapped-operand accumulation: accT[n][m] = mfma(w_frag, x_frag, accT)
// computes out^T fragment-wise; lane mapping (col=lane&15 -> out ROW,
// row=(lane>>4)*4+reg -> 4 consecutive out COLS) => float4 stores.
// Skeleton (XOR swizzle both-sides, counted-vmcnt dbuf pipeline) unchanged.
// ---------------------------------------------------------------------------
__global__ __launch_bounds__(256) void lora_main(
    const unsigned short* __restrict__ xf, const unsigned short* __restrict__ wf,
    const float* __restrict__ bias, const float* __restrict__ Bm,
    const int* __restrict__ tuner, const unsigned short* __restrict__ lowb,
    float* __restrict__ out) {
  __shared__ __align__(16) unsigned char smem[32768];
  const int tid  = threadIdx.x;
  const int lane = tid & 63;
  const int w    = tid >> 6;

  // XCD swizzle (1024 blocks, %8==0 -> simple form is bijective)
  const int swz = ((int)blockIdx.x & 7) * 128 + ((int)blockIdx.x >> 3);
  const int bm = swz >> 3, bn = swz & 7;
  const size_t i0 = (size_t)bm * 128, j0 = (size_t)bn * 128;
  const int wm = w >> 1, wn = w & 1;

  // staging: waves 0,1 stage xf rows i0+{0..63},{64..127}; waves 2,3 stage wf.
  const int wp = w & 1;
  const unsigned short* gsrc = (w < 2) ? xf : wf;
  const size_t grow0 = ((w < 2) ? i0 : j0) + wp * 64;
  const unsigned short* gbase =
      gsrc + (grow0 + (lane >> 2)) * kDin + ((lane & 3) ^ ((lane >> 3) & 3)) * 8;
  const int stoff = (w >> 1) * 8192 + wp * 4096;  // this wave's dest region

  f32x4 acc[4][4];   // acc[n][m] = out^T fragment
#pragma unroll
  for (int n = 0; n < 4; ++n)
#pragma unroll
    for (int m = 0; m < 4; ++m) acc[n][m] = (f32x4){0.f, 0.f, 0.f, 0.f};

  const int kg = lane >> 4;   // k-group 0..3 (8 fp16 each)
  const int rl = lane & 15;
  // swizzled read: chunk kg of row r lives at position kg^((r>>1)&3)
  const int csw = kg ^ ((rl >> 1) & 3);
  const int rdA = (wm * 64 + rl) * 64 + csw * 16;           // x region [0,8K)
  const int rdB = 8192 + (wn * 64 + rl) * 64 + csw * 16;    // w region [8K,16K)

  auto compute_step = [&](const unsigned char* B0) {
    f16x8 a[4], b[4];
#pragma unroll
    for (int m = 0; m < 4; ++m) {
      a[m] = *(const f16x8*)(B0 + rdA + m * 1024);
      b[m] = *(const f16x8*)(B0 + rdB + m * 1024);
    }
    __builtin_amdgcn_s_setprio(1);
#pragma unroll
    for (int n = 0; n < 4; ++n)
#pragma unroll
      for (int m = 0; m < 4; ++m)
        acc[n][m] = mfma_f16(b[n], a[m], acc[n][m]);   // swapped: W as A-operand
    __builtin_amdgcn_s_setprio(0);
  };

  // prologue: stage K-step 0 into buf0 (4 loads/wave in flight)
  {
    unsigned char* dst = smem + stoff;
#pragma unroll
    for (int c = 0; c < 4; ++c)
      gload_lds16(gbase + c * 16 * kDin, dst + c * 1024);
  }

  for (int s = 0; s < 31; ++s) {
    const int p = s & 1;
    {  // prefetch step s+1 into buf p^1
      unsigned char* dst = smem + (p ^ 1) * 16384 + stoff;
      const unsigned short* src = gbase + (s + 1) * 32;
#pragma unroll
      for (int c = 0; c < 4; ++c)
        gload_lds16(src + c * 16 * kDin, dst + c * 1024);
    }
    asm volatile("s_waitcnt vmcnt(4)" ::: "memory");  // step-s loads landed
    __builtin_amdgcn_s_barrier();
    asm volatile("" ::: "memory");
    compute_step(smem + p * 16384);
    asm volatile("s_waitcnt lgkmcnt(0)" ::: "memory");  // buf-p reads retired
    __builtin_amdgcn_s_barrier();                       // buf p reusable
    asm volatile("" ::: "memory");
  }
  asm volatile("s_waitcnt vmcnt(0)" ::: "memory");
  __builtin_amdgcn_s_barrier();
  asm volatile("" ::: "memory");
  compute_step(smem + 16384);

  // bias: lane's 4 consecutive out cols = j0 + wn*64 + n*16 + kg*4 + {0..3}
#pragma unroll
  for (int n = 0; n < 4; ++n) {
    const f32x4 bv = *(const f32x4*)(bias + j0 + wn * 64 + n * 16 + kg * 4);
#pragma unroll
    for (int m = 0; m < 4; ++m)
#pragma unroll
      for (int r = 0; r < 4; ++r) acc[n][m][r] += bv[r];
  }

  // Epilogue tiles in [0,16K): Lt (low) at [0,8192), Mt (Bm) at [8192,16384),
  // fragment-major [kg(4)][row(128)][16B]; zero kg2-3 pads (K=16..31).
  {
    unsigned char* p = (tid < 128) ? (smem + 4096 + tid * 32)
                                   : (smem + 12288 + (tid - 128) * 32);
    const us8 z = {0, 0, 0, 0, 0, 0, 0, 0};
    *(us8*)p = z;
    *(us8*)(p + 16) = z;
  }

  for (int t = 0; t < kT; ++t) {
    __syncthreads();  // zeros visible / previous t's reads done
    {
      const int row = tid >> 1, half = tid & 1;
      const us8 lv = *(const us8*)(lowb + ((size_t)t * kM + i0 + row) * kR + half * 8);
      *(us8*)(smem + half * 2048 + row * 16) = lv;
      const int ti = tuner[t];
      const float* bp = Bm + ((size_t)ti * kDout + j0 + row) * kR + half * 8;
      const float4 m0 = *(const float4*)bp;
      const float4 m1 = *(const float4*)(bp + 4);
      us8 mv;
      mv[0] = f2h(m0.x); mv[1] = f2h(m0.y); mv[2] = f2h(m0.z); mv[3] = f2h(m0.w);
      mv[4] = f2h(m1.x); mv[5] = f2h(m1.y); mv[6] = f2h(m1.z); mv[7] = f2h(m1.w);
      *(us8*)(smem + 8192 + half * 2048 + row * 16) = mv;
    }
    __syncthreads();

    f16x8 lf[4], mf[4];
#pragma unroll
    for (int m = 0; m < 4; ++m)
      lf[m] = *(const f16x8*)(smem + kg * 2048 + (wm * 64 + m * 16 + rl) * 16);
#pragma unroll
    for (int n = 0; n < 4; ++n)
      mf[n] = *(const f16x8*)(smem + 8192 + kg * 2048 + (wn * 64 + n * 16 + rl) * 16);

#pragma unroll
    for (int n = 0; n < 4; ++n)
#pragma unroll
      for (int m = 0; m < 4; ++m) {
        const f32x4 d = mfma_f16(mf[n], lf[m], acc[n][m]);  // swapped, = out^T
        const size_t row = (size_t)t * kM + i0 + wm * 64 + m * 16 + rl;
        const int    col = (int)j0 + wn * 64 + n * 16 + kg * 4;
        *(f32x4*)(out + row * kDout + col) = d;             // float4 store
      }
  }
}

// ---------------------------------------------------------------------------
extern "C" void kernel_launch(void* const* d_in, const int* in_sizes, int n_in,
                              void* d_out, int out_size, void* d_ws, size_t ws_size,
                              hipStream_t stream) {
  const float* x    = (const float*)d_in[0];
  const float* W    = (const float*)d_in[1];
  const float* bias = (const float*)d_in[2];
  const float* lA   = (const float*)d_in[3];
  const float* lB   = (const float*)d_in[4];
  const int*   ti   = (const int*)d_in[5];
  float* out = (float*)d_out;

  unsigned char* ws = (unsigned char*)d_ws;
  unsigned short* xfp  = (unsigned short*)(ws + OFF_XF);
  unsigned short* wfp  = (unsigned short*)(ws + OFF_WF);
  unsigned short* lowb = (unsigned short*)(ws + OFF_LOW);

  cvt_W<<<64, 256, 0, stream>>>(W, wfp);
  lora_low<<<kM / 32, 256, 0, stream>>>(x, lA, ti, lowb, xfp);
  lora_main<<<1024, 256, 0, stream>>>(xfp, wfp, bias, lB, ti, lowb, out);
}

// Round 9
// 159.628 us; speedup vs baseline: 1.0690x; 1.0690x over previous
//
#include <hip/hip_runtime.h>

// out[t][i][j] = sum_k x[i][k]*W[j][k] + bias[j] + sum_r low[t][i][r]*Bm[ti][j][r]
// low[t][i][r] = sum_k x[i][k]*A[ti][r][k]
// Base GEMM in single-stream fp16 MFMA. v6:
//  - lora_main tile 128x64, grid 2048 (~6/CU resident of 8 needed) so block
//    cohorts stagger: store-drain of finishing blocks overlaps K-loops of
//    launching blocks (round-8 analysis: lockstep write burst was the stall).
//  - nontemporal out stores (write-once; don't evict xf/wf from L2).
//  - cvt_W folded into lora_low prelude (one less kernel).

typedef __attribute__((ext_vector_type(8))) _Float16 f16x8;
typedef __attribute__((ext_vector_type(4))) float f32x4;
typedef __attribute__((ext_vector_type(4))) unsigned short us4;
typedef __attribute__((ext_vector_type(8))) unsigned short us8;

namespace {
constexpr int kM = 16384, kDin = 1024, kDout = 1024, kR = 16, kT = 4;
constexpr size_t OFF_XF  = 0;               // [16384][1024] fp16 = 32 MiB
constexpr size_t OFF_WF  = 33554432;        // [1024][1024] fp16 = 2 MiB
constexpr size_t OFF_LOW = 35651584;        // [4][16384][16] fp16 = 2 MiB
}

__device__ inline unsigned short f2h(float f) {
  _Float16 h = (_Float16)f;  // RNE
  return __builtin_bit_cast(unsigned short, h);
}
__device__ inline void gload_lds16(const void* g, void* l) {
  __builtin_amdgcn_global_load_lds(
      (const __attribute__((address_space(1))) unsigned int*)g,
      (__attribute__((address_space(3))) unsigned int*)l, 16, 0, 0);
}
__device__ inline f32x4 mfma_f16(f16x8 a, f16x8 b, f32x4 c) {
  return __builtin_amdgcn_mfma_f32_16x16x32_f16(a, b, c, 0, 0, 0);
}

// ---------------------------------------------------------------------------
// Kernel 1: W fp32->fp16 prelude + low[t][i][r] = x[i].A[ti][r] (+ xf = fp16(x))
// ---------------------------------------------------------------------------
__global__ __launch_bounds__(256) void lora_low(const float* __restrict__ x,
                                                const float* __restrict__ W,
                                                const float* __restrict__ A,
                                                const int* __restrict__ tuner,
                                                unsigned short* __restrict__ lowb,
                                                unsigned short* __restrict__ xf,
                                                unsigned short* __restrict__ wf) {
  // --- prelude: convert W (1024x1024) to fp16; 512 blocks x 256 thr x 2 items
  {
    const int idx = blockIdx.x * 256 + threadIdx.x;
#pragma unroll
    for (int p = 0; p < 2; ++p) {
      const int j = idx + p * 131072;
      const float4 v = ((const float4*)W)[j];
      us4 h;
      h[0] = f2h(v.x); h[1] = f2h(v.y); h[2] = f2h(v.z); h[3] = f2h(v.w);
      ((us4*)wf)[j] = h;
    }
  }

  __shared__ float xs[64][34];  // [k][row]
  __shared__ float as[64][66];  // [k][t*16+r]
  const int tid = threadIdx.x;
  const int i0  = blockIdx.x * 32;
  const int tx  = tid & 15;
  const int ty  = tid >> 4;
  float acc[2][4] = {{0.f, 0.f, 0.f, 0.f}, {0.f, 0.f, 0.f, 0.f}};

  for (int kt = 0; kt < kDin; kt += 64) {
    __syncthreads();
#pragma unroll
    for (int p = 0; p < 2; ++p) {  // x tile: 32 rows x 64 k (+ fused xf store)
      const int f = tid + p * 256;
      const int row = f >> 4, kq = (f & 15) * 4;
      const float4 v = *(const float4*)(x + (size_t)(i0 + row) * kDin + kt + kq);
      xs[kq + 0][row] = v.x; xs[kq + 1][row] = v.y;
      xs[kq + 2][row] = v.z; xs[kq + 3][row] = v.w;
      us4 h;
      h[0] = f2h(v.x); h[1] = f2h(v.y); h[2] = f2h(v.z); h[3] = f2h(v.w);
      *(us4*)(xf + (size_t)(i0 + row) * kDin + kt + kq) = h;
    }
#pragma unroll
    for (int p = 0; p < 4; ++p) {  // A tile: 64 (t,r) rows x 64 k
      const int f = tid + p * 256;
      const int ar = f >> 4, kq = (f & 15) * 4;
      const int ti = tuner[ar >> 4];
      const float4 v = *(const float4*)(A + ((size_t)ti * kR + (ar & 15)) * kDin + kt + kq);
      as[kq + 0][ar] = v.x; as[kq + 1][ar] = v.y;
      as[kq + 2][ar] = v.z; as[kq + 3][ar] = v.w;
    }
    __syncthreads();
#pragma unroll 8
    for (int k = 0; k < 64; ++k) {
      const float a0 = xs[k][ty * 2], a1 = xs[k][ty * 2 + 1];
      const float b0 = as[k][tx * 4], b1 = as[k][tx * 4 + 1];
      const float b2 = as[k][tx * 4 + 2], b3 = as[k][tx * 4 + 3];
      acc[0][0] += a0 * b0; acc[0][1] += a0 * b1; acc[0][2] += a0 * b2; acc[0][3] += a0 * b3;
      acc[1][0] += a1 * b0; acc[1][1] += a1 * b1; acc[1][2] += a1 * b2; acc[1][3] += a1 * b3;
    }
  }
#pragma unroll
  for (int ii = 0; ii < 2; ++ii) {
    us4 o;
#pragma unroll
    for (int j = 0; j < 4; ++j) o[j] = f2h(acc[ii][j]);
    *(us4*)(lowb + ((size_t)(tx >> 2) * kM + i0 + ty * 2 + ii) * kR + (tx & 3) * 4) = o;
  }
}

// ---------------------------------------------------------------------------
// Kernel 2: main fp16 MFMA GEMM, tile 128x64 (BK=32), grid 2048, + per-t
// rank-16 K-extension epilogue. Counted-vmcnt dbuf pipeline; XOR swizzle
// both-sides; swapped-operand MFMA -> float4 nontemporal stores.
// LDS: 2 buffers x 12KB (A [0,8K) 128 rows, B [8K,12K) 64 rows).
// Staging: 12 gload_lds/step, 3 per wave (c = 3w+q; c<8 -> A, else B).
// ---------------------------------------------------------------------------
__global__ __launch_bounds__(256) void lora_main(
    const unsigned short* __restrict__ xf, const unsigned short* __restrict__ wf,
    const float* __restrict__ bias, const float* __restrict__ Bm,
    const int* __restrict__ tuner, const unsigned short* __restrict__ lowb,
    float* __restrict__ out) {
  __shared__ __align__(16) unsigned char smem[24576];
  const int tid  = threadIdx.x;
  const int lane = tid & 63;
  const int w    = tid >> 6;

  // XCD swizzle (2048 blocks, %8==0 -> bijective)
  const int swz = ((int)blockIdx.x & 7) * 256 + ((int)blockIdx.x >> 3);
  const int bm = swz >> 4, bn = swz & 15;
  const size_t i0 = (size_t)bm * 128, j0 = (size_t)bn * 64;
  const int wm = w >> 1, wn = w & 1;   // wave tile: rows wm*64, cols wn*32

  // staging sources: 3 chunks per wave, c = 3w+q; chunk-swizzled within row
  const int chsw = ((lane & 3) ^ ((lane >> 3) & 3)) * 8;
  const unsigned short* gsrc_q[3];
  int ldsoff_q[3];
#pragma unroll
  for (int q = 0; q < 3; ++q) {
    const int c = 3 * w + q;
    const bool isA = c < 8;
    const size_t rowb = (isA ? i0 + c * 16 : j0 + (c - 8) * 16) + (lane >> 2);
    gsrc_q[q] = (isA ? xf : wf) + rowb * kDin + chsw;
    ldsoff_q[q] = c * 1024;
  }

  f32x4 acc[2][4];   // acc[n][m] = out^T fragments
#pragma unroll
  for (int n = 0; n < 2; ++n)
#pragma unroll
    for (int m = 0; m < 4; ++m) acc[n][m] = (f32x4){0.f, 0.f, 0.f, 0.f};

  const int kg = lane >> 4;
  const int rl = lane & 15;
  const int csw = kg ^ ((rl >> 1) & 3);
  const int rdA = (wm * 64 + rl) * 64 + csw * 16;          // A region [0,8K)
  const int rdB = 8192 + (wn * 32 + rl) * 64 + csw * 16;   // B region [8K,12K)

  auto compute_step = [&](const unsigned char* B0) {
    f16x8 a[4], b[2];
#pragma unroll
    for (int m = 0; m < 4; ++m) a[m] = *(const f16x8*)(B0 + rdA + m * 1024);
#pragma unroll
    for (int n = 0; n < 2; ++n) b[n] = *(const f16x8*)(B0 + rdB + n * 1024);
    __builtin_amdgcn_s_setprio(1);
#pragma unroll
    for (int n = 0; n < 2; ++n)
#pragma unroll
      for (int m = 0; m < 4; ++m)
        acc[n][m] = mfma_f16(b[n], a[m], acc[n][m]);   // swapped: W as A-operand
    __builtin_amdgcn_s_setprio(0);
  };

  // prologue: stage K-step 0 into buf0 (3 loads/wave)
#pragma unroll
  for (int q = 0; q < 3; ++q)
    gload_lds16(gsrc_q[q], smem + ldsoff_q[q]);

  for (int s = 0; s < 31; ++s) {
    const int p = s & 1;
    {  // prefetch step s+1 into buf p^1 (6 loads/wave outstanding)
      unsigned char* dst = smem + (p ^ 1) * 12288;
      const int ko = (s + 1) * 32;
#pragma unroll
      for (int q = 0; q < 3; ++q)
        gload_lds16(gsrc_q[q] + ko, dst + ldsoff_q[q]);
    }
    asm volatile("s_waitcnt vmcnt(3)" ::: "memory");  // step-s loads landed
    __builtin_amdgcn_s_barrier();
    asm volatile("" ::: "memory");
    compute_step(smem + p * 12288);
    asm volatile("s_waitcnt lgkmcnt(0)" ::: "memory");
    __builtin_amdgcn_s_barrier();
    asm volatile("" ::: "memory");
  }
  asm volatile("s_waitcnt vmcnt(0)" ::: "memory");
  __builtin_amdgcn_s_barrier();
  asm volatile("" ::: "memory");
  compute_step(smem + 12288);   // peeled step 31 reads buf1

  // bias: lane's 4 consecutive out cols = j0 + wn*32 + n*16 + kg*4 + {0..3}
#pragma unroll
  for (int n = 0; n < 2; ++n) {
    const f32x4 bv = *(const f32x4*)(bias + j0 + wn * 32 + n * 16 + kg * 4);
#pragma unroll
    for (int m = 0; m < 4; ++m)
#pragma unroll
      for (int r = 0; r < 4; ++r) acc[n][m][r] += bv[r];
  }

  // Epilogue tiles in buf0 [0,12288): Lt [kg4][128][16] at [0,8K),
  // Mt [kg4][64][16] at [8K,12K). Zero kg2-3 pads.
  {
    if (tid < 128) {
      const us8 z = {0, 0, 0, 0, 0, 0, 0, 0};
      *(us8*)(smem + 4096 + tid * 32) = z;        // Lt pad [4096,8192)
      *(us8*)(smem + 4096 + tid * 32 + 16) = z;
    } else if (tid < 192) {
      const us8 z = {0, 0, 0, 0, 0, 0, 0, 0};
      *(us8*)(smem + 10240 + (tid - 128) * 32) = z;  // Mt pad [10240,12288)
      *(us8*)(smem + 10240 + (tid - 128) * 32 + 16) = z;
    }
  }

  for (int t = 0; t < kT; ++t) {
    __syncthreads();  // zeros/previous-t reads done before restage
    {
      const int row = tid >> 1, half = tid & 1;
      // Lt (low tile, fp16): 128 rows
      const us8 lv = *(const us8*)(lowb + ((size_t)t * kM + i0 + row) * kR + half * 8);
      *(us8*)(smem + half * 2048 + row * 16) = lv;
      if (tid < 128) {  // Mt (Bm tile, fp32->fp16): 64 rows
        const int ti = tuner[t];
        const float* bp = Bm + ((size_t)ti * kDout + j0 + row) * kR + half * 8;
        const float4 m0 = *(const float4*)bp;
        const float4 m1 = *(const float4*)(bp + 4);
        us8 mv;
        mv[0] = f2h(m0.x); mv[1] = f2h(m0.y); mv[2] = f2h(m0.z); mv[3] = f2h(m0.w);
        mv[4] = f2h(m1.x); mv[5] = f2h(m1.y); mv[6] = f2h(m1.z); mv[7] = f2h(m1.w);
        *(us8*)(smem + 8192 + half * 1024 + row * 16) = mv;
      }
    }
    __syncthreads();

    f16x8 lf[4], mf[2];
#pragma unroll
    for (int m = 0; m < 4; ++m)
      lf[m] = *(const f16x8*)(smem + kg * 2048 + (wm * 64 + m * 16 + rl) * 16);
#pragma unroll
    for (int n = 0; n < 2; ++n)
      mf[n] = *(const f16x8*)(smem + 8192 + kg * 1024 + (wn * 32 + n * 16 + rl) * 16);

#pragma unroll
    for (int n = 0; n < 2; ++n)
#pragma unroll
      for (int m = 0; m < 4; ++m) {
        const f32x4 d = mfma_f16(mf[n], lf[m], acc[n][m]);  // = out^T fragment
        const size_t row = (size_t)t * kM + i0 + wm * 64 + m * 16 + rl;
        const int    col = (int)j0 + wn * 32 + n * 16 + kg * 4;
        __builtin_nontemporal_store(d, (f32x4*)(out + row * kDout + col));
      }
  }
}

// ---------------------------------------------------------------------------
extern "C" void kernel_launch(void* const* d_in, const int* in_sizes, int n_in,
                              void* d_out, int out_size, void* d_ws, size_t ws_size,
                              hipStream_t stream) {
  const float* x    = (const float*)d_in[0];
  const float* W    = (const float*)d_in[1];
  const float* bias = (const float*)d_in[2];
  const float* lA   = (const float*)d_in[3];
  const float* lB   = (const float*)d_in[4];
  const int*   ti   = (const int*)d_in[5];
  float* out = (float*)d_out;

  unsigned char* ws = (unsigned char*)d_ws;
  unsigned short* xfp  = (unsigned short*)(ws + OFF_XF);
  unsigned short* wfp  = (unsigned short*)(ws + OFF_WF);
  unsigned short* lowb = (unsigned short*)(ws + OFF_LOW);

  lora_low<<<kM / 32, 256, 0, stream>>>(x, W, lA, ti, lowb, xfp, wfp);
  lora_main<<<2048, 256, 0, stream>>>(xfp, wfp, bias, lB, ti, lowb, out);
}